// Round 3
// baseline (255.641 us; speedup 1.0000x reference)
//
#include <hip/hip_runtime.h>
#include <hip/hip_bf16.h>

#define FS 24
#define NPATCH 576
#define EMBD 768
#define KDIM 768
#define NB 64
#define IMGW 384
#define MTOT (NB*NPATCH)       // 36864
#define EPSV 1e-4f

#define O2_OFS (MTOT*EMBD)     // 28311552
#define G1_OFS (2*O2_OFS)      // 56623104
#define G2_OFS (G1_OFS + NB*4)

// workspace float-region layout (float indices at byte offset 0)
#define WS_G1 0
#define WS_G2 256
#define WS_SK1 512
#define WS_SK2 576
#define WS_MEAN1 1024
#define WS_STD1 (WS_MEAN1 + NB*EMBD)
#define WS_MEAN2 (WS_STD1 + NB*EMBD)
#define WS_STD2 (WS_MEAN2 + NB*EMBD)

// byte-region layout for the bf16 fast path
#define WSB_W  1048576ULL                     // Wb: 768*768*2 = 1179648 B
#define WSB_IM (WSB_W + 1179648ULL)           // im: 36864*768*2 = 56623104 B
#define WS_NEED (WSB_IM + 56623104ULL)

// GEMM geometry: BM=256, BN=128, BK=64, 3-deep ring
#define TILE_A_SZ 32768
#define TILE_B_SZ 16384
#define BUF_SZ    49152

typedef __attribute__((ext_vector_type(8))) short bf16x8;
typedef __attribute__((ext_vector_type(4))) unsigned short u16x4;
typedef __attribute__((ext_vector_type(8))) unsigned short u16x8;
typedef __attribute__((ext_vector_type(4))) float f32x4;

__device__ __forceinline__ u16x4 cvt4_bf16(f32x4 v) {
    u16x4 r;
#pragma unroll
    for (int j = 0; j < 4; ++j) r[j] = __builtin_bit_cast(unsigned short, (__bf16)v[j]);
    return r;
}

__device__ __forceinline__ void gload16(const void* g, const void* l) {
    __builtin_amdgcn_global_load_lds(
        (const __attribute__((address_space(1))) unsigned int*)g,
        (__attribute__((address_space(3))) unsigned int*)l, 16, 0, 0);
}

// ---------------- boxes: per-batch scalar pipeline (exact f32 port) ----------
__device__ inline float occ_of(const float b1[4], const float b2[4]) {
    float ixmin = fmaxf(b1[0], b2[0]);
    float iymin = fmaxf(b1[1], b2[1]);
    float ixmax = fminf(b1[2], b2[2]);
    float iymax = fminf(b1[3], b2[3]);
    float iv = fmaxf(iymax - iymin, 0.f) * fmaxf(ixmax - ixmin, 0.f);
    float v1 = (b1[2] - b1[0]) * (b1[3] - b1[1]);
    return (iv + 1e-8f) / (v1 + 1e-8f);
}

__device__ inline void upd_box(const float* b1, const float* b2, float* o) {
    float x0 = b1[0], y0 = b1[1], x2 = b1[2], y2 = b1[3];
    float q0 = b2[0], q1 = b2[1], q2 = b2[2], q3 = b2[3];
    bool condA = (x0 >= q0) && (x2 <= q2);
    bool subA1 = (q1 <= y0) && (q3 > y0);
    bool a1 = condA && subA1;
    bool a2 = condA && !subA1 && (q3 >= y2) && (q1 < y2);
    bool condB = !condA && (y0 >= q1) && (y2 <= q3);
    bool subB1 = (q0 <= x0) && (q2 > x0);
    bool bb1 = condB && subB1;
    bool bb2 = condB && !subB1 && (q2 >= x2) && (q0 < x2);
    o[1] = a1 ? q3 : y0;
    o[3] = a2 ? q1 : y2;
    o[0] = bb1 ? q2 : x0;
    o[2] = bb2 ? q0 : x2;
}

__global__ void boxes_kernel(const float* __restrict__ gt1, const float* __restrict__ gt2,
                             float* __restrict__ gout1, float* __restrict__ gout2,
                             float* __restrict__ ws) {
    const int b = threadIdx.x;
    if (b >= NB) return;
    float g1[4], g2[4];
    {
        float p0 = gt1[b*4+0]*(float)IMGW, p1 = gt1[b*4+1]*(float)IMGW;
        float p2 = gt1[b*4+2]*(float)IMGW, p3 = gt1[b*4+3]*(float)IMGW;
        g1[0] = rintf(p0 / 16.f);
        g1[1] = rintf(p1 / 16.f);
        g1[2] = rintf((p0 + p2 - 1.f) / 16.f);
        g1[3] = rintf((p1 + p3 - 1.f) / 16.f);
    }
    {
        float p0 = gt2[b*4+0]*(float)IMGW, p1 = gt2[b*4+1]*(float)IMGW;
        float p2 = gt2[b*4+2]*(float)IMGW, p3 = gt2[b*4+3]*(float)IMGW;
        g2[0] = rintf(p0 / 16.f);
        g2[1] = rintf(p1 / 16.f);
        g2[2] = rintf((p0 + p2 - 1.f) / 16.f);
        g2[3] = rintf((p1 + p3 - 1.f) / 16.f);
    }
    float occ1 = occ_of(g1, g2), occ2 = occ_of(g2, g1);
    const float fsf = (float)FS;
    bool skip1 = (occ1 > 0.5f) || (g2[3] <= g2[1]) || (g2[2] <= g2[0]) ||
                 (g2[0] < 0.f) || (g2[1] < 0.f) || (g2[0] >= fsf) || (g2[1] >= fsf);
    bool skip2 = (occ2 > 0.5f) || (g1[3] <= g1[1]) || (g1[2] <= g1[0]) ||
                 (g1[0] < 0.f) || (g1[1] < 0.f) || (g1[0] >= fsf) || (g1[1] >= fsf);

    float n1[4], n2[4];
    upd_box(g1, g2, n1);
    upd_box(g2, g1, n2);
    if (skip1) { n1[0]=g1[0]; n1[1]=g1[1]; n1[2]=g1[2]; n1[3]=g1[3]; }
    if (skip2) { n2[0]=g2[0]; n2[1]=g2[1]; n2[2]=g2[2]; n2[3]=g2[3]; }

    gout1[b*4+0] = n1[0]; gout1[b*4+1] = n1[1];
    gout1[b*4+2] = n1[2] - n1[0]; gout1[b*4+3] = n1[3] - n1[1];
    gout2[b*4+0] = n2[0]; gout2[b*4+1] = n2[1];
    gout2[b*4+2] = n2[2] - n2[0]; gout2[b*4+3] = n2[3] - n2[1];

#pragma unroll
    for (int i = 0; i < 4; ++i) { ws[WS_G1 + b*4 + i] = g1[i]; ws[WS_G2 + b*4 + i] = g2[i]; }
    ws[WS_SK1 + b] = skip1 ? 1.f : 0.f;
    ws[WS_SK2 + b] = skip2 ? 1.f : 0.f;
}

// ---- pre-convert W f32 -> bf16, chunk-swizzled: chunk c of each 64-elem
// k-block stored at position c ^ (row&7)  (T2 pre-swizzled-source pattern)
__global__ void cvt_w_kernel(const float* __restrict__ Wm, unsigned short* __restrict__ Wb) {
    const int idx = blockIdx.x * 256 + threadIdx.x;   // 73728 = 768 rows * 96 chunks
    const int n = idx / 96;
    const int c = idx - n * 96;
    const f32x4 a = *reinterpret_cast<const f32x4*>(Wm + idx*8);
    const f32x4 b = *reinterpret_cast<const f32x4*>(Wm + idx*8 + 4);
    u16x8 r;
    u16x4 lo = cvt4_bf16(a), hi = cvt4_bf16(b);
#pragma unroll
    for (int j = 0; j < 4; ++j) { r[j] = lo[j]; r[j+4] = hi[j]; }
    const int pos = ((c >> 3) << 6) + (((c & 7) ^ (n & 7)) << 3);
    *reinterpret_cast<u16x8*>(Wb + (size_t)n*KDIM + pos) = r;
}

// ---- x f32 NCHW -> bf16 im2col [36864][768], chunk-swizzled like Wb --------
__global__ void im2col_kernel(const float* __restrict__ xin, unsigned short* __restrict__ im) {
    const int idx = blockIdx.x * 256 + threadIdx.x;   // 36864*96
    const int m  = idx / 96;
    const int kc = idx - m * 96;
    const int c   = kc >> 5;            // channel
    const int rem = kc & 31;
    const int i   = rem >> 1;
    const int j0  = (rem & 1) * 8;
    const int b = m / NPATCH;
    const int p = m - b * NPATCH;
    const int py = p / FS, px = p - py * FS;
    const int src = ((b*3 + c)*IMGW + py*16 + i)*IMGW + px*16 + j0;
    const f32x4 a0 = *reinterpret_cast<const f32x4*>(xin + src);
    const f32x4 a1 = *reinterpret_cast<const f32x4*>(xin + src + 4);
    u16x8 r;
    u16x4 lo = cvt4_bf16(a0), hi = cvt4_bf16(a1);
#pragma unroll
    for (int j = 0; j < 4; ++j) { r[j] = lo[j]; r[j+4] = hi[j]; }
    const int e = (c << 8) + (i << 4) + j0;                    // original k offset
    const int eswz = (e & ~63) | ((((e >> 3) & 7) ^ (m & 7)) << 3);
    *reinterpret_cast<u16x8*>(im + (size_t)m*KDIM + eswz) = r;
}

// ---- bf16 GEMM: 256x128 tile, BK=64, 3-deep ring, counted vmcnt, setprio ---
__global__ __launch_bounds__(512, 2)
void gemm8_kernel(const unsigned short* __restrict__ A,
                  const unsigned short* __restrict__ Bw,
                  const float* __restrict__ bias,
                  float* __restrict__ oo) {
    __shared__ __align__(16) unsigned char lds[3*BUF_SZ];   // 144 KiB

    const int bx = blockIdx.x;                 // 864 = 8 * 108
    const int swz = (bx & 7) * 108 + (bx >> 3);
    const int mt = swz / 6;
    const int nt = swz - mt * 6;
    const int m0 = mt * 256, n0 = nt * 128;

    const int tid = threadIdx.x;
    const int wid = tid >> 6;
    const int lane = tid & 63;
    const int wm = wid >> 1, wn = wid & 1;     // 4M x 2N waves
    const int fr = lane & 15, fq = lane >> 4;

    // staging source offsets (bytes), linear in the pre-swizzled buffers
    const int srow = tid >> 3;                 // 0..63
    const int scb  = (tid & 7) * 16;
    size_t aoff[4], boff[2];
#pragma unroll
    for (int j = 0; j < 4; ++j) aoff[j] = (size_t)(m0 + j*64 + srow)*1536 + scb;
#pragma unroll
    for (int j = 0; j < 2; ++j) boff[j] = (size_t)(n0 + j*64 + srow)*1536 + scb;
    const int ldsuni = wid * 1024;             // wave-uniform LDS base part

    const char* Ab = (const char*)A;
    const char* Bb = (const char*)Bw;

    f32x4 acc[4][4];
#pragma unroll
    for (int i = 0; i < 4; ++i)
#pragma unroll
        for (int j = 0; j < 4; ++j) acc[i][j] = (f32x4){0.f, 0.f, 0.f, 0.f};

    // prologue: kt0 -> buf0, kt1 -> buf1 (12 gloads/thread)
#pragma unroll
    for (int j = 0; j < 4; ++j) gload16(Ab + aoff[j],       lds + j*8192 + ldsuni);
#pragma unroll
    for (int j = 0; j < 2; ++j) gload16(Bb + boff[j],       lds + TILE_A_SZ + j*8192 + ldsuni);
#pragma unroll
    for (int j = 0; j < 4; ++j) gload16(Ab + aoff[j] + 128, lds + BUF_SZ + j*8192 + ldsuni);
#pragma unroll
    for (int j = 0; j < 2; ++j) gload16(Bb + boff[j] + 128, lds + BUF_SZ + TILE_A_SZ + j*8192 + ldsuni);
    asm volatile("s_waitcnt vmcnt(6)" ::: "memory");   // kt0 landed, kt1 in flight
    __builtin_amdgcn_s_barrier();

    int s = 0;
    for (int kt = 0; kt < 12; ++kt) {
        const unsigned char* As_ = lds + s*BUF_SZ;
        const unsigned char* Bs_ = As_ + TILE_A_SZ;
        const int s2 = (s + 2 >= 3) ? s - 1 : s + 2;   // ring slot for kt+2
        const bool doSt = (kt + 2 < 12);
        const size_t kb = (size_t)(kt + 2) * 128;
        unsigned char* St = lds + s2*BUF_SZ;

        bf16x8 afr[4][2], bfr[2][2];
        // ---- phase 0: read all A frags + B nf=0,1; stage A rounds 0-2 ----
#pragma unroll
        for (int mf = 0; mf < 4; ++mf) {
            const int r = wm*64 + mf*16 + fr;
            const int sw = (r & 7) << 4;
#pragma unroll
            for (int ko = 0; ko < 2; ++ko)
                afr[mf][ko] = *reinterpret_cast<const bf16x8*>(
                    As_ + r*128 + ((ko*64 + fq*16) ^ sw));
        }
#pragma unroll
        for (int nf = 0; nf < 2; ++nf) {
            const int rn = wn*64 + nf*16 + fr;
            const int sw = (rn & 7) << 4;
#pragma unroll
            for (int ko = 0; ko < 2; ++ko)
                bfr[nf][ko] = *reinterpret_cast<const bf16x8*>(
                    Bs_ + rn*128 + ((ko*64 + fq*16) ^ sw));
        }
        if (doSt) {
            gload16(Ab + aoff[0] + kb, St + 0*8192 + ldsuni);
            gload16(Ab + aoff[1] + kb, St + 1*8192 + ldsuni);
            gload16(Ab + aoff[2] + kb, St + 2*8192 + ldsuni);
        }
        __builtin_amdgcn_s_barrier();
        __builtin_amdgcn_s_setprio(1);
#pragma unroll
        for (int mf = 0; mf < 4; ++mf)
#pragma unroll
            for (int nf = 0; nf < 2; ++nf)
#pragma unroll
                for (int ko = 0; ko < 2; ++ko)
                    acc[mf][nf] = __builtin_amdgcn_mfma_f32_16x16x32_bf16(
                        afr[mf][ko], bfr[nf][ko], acc[mf][nf], 0, 0, 0);
        __builtin_amdgcn_s_setprio(0);
        __builtin_amdgcn_s_barrier();

        // ---- phase 1: read B nf=2,3; stage A round 3 + B rounds 0-1 ----
#pragma unroll
        for (int nf = 0; nf < 2; ++nf) {
            const int rn = wn*64 + (nf+2)*16 + fr;
            const int sw = (rn & 7) << 4;
#pragma unroll
            for (int ko = 0; ko < 2; ++ko)
                bfr[nf][ko] = *reinterpret_cast<const bf16x8*>(
                    Bs_ + rn*128 + ((ko*64 + fq*16) ^ sw));
        }
        if (doSt) {
            gload16(Ab + aoff[3] + kb, St + 3*8192 + ldsuni);
            gload16(Bb + boff[0] + kb, St + TILE_A_SZ + 0*8192 + ldsuni);
            gload16(Bb + boff[1] + kb, St + TILE_A_SZ + 1*8192 + ldsuni);
        }
        __builtin_amdgcn_s_barrier();
        __builtin_amdgcn_s_setprio(1);
#pragma unroll
        for (int mf = 0; mf < 4; ++mf)
#pragma unroll
            for (int nf = 0; nf < 2; ++nf)
#pragma unroll
                for (int ko = 0; ko < 2; ++ko)
                    acc[mf][nf+2] = __builtin_amdgcn_mfma_f32_16x16x32_bf16(
                        afr[mf][ko], bfr[nf][ko], acc[mf][nf+2], 0, 0, 0);
        __builtin_amdgcn_s_setprio(0);
        if (kt <= 9)       asm volatile("s_waitcnt vmcnt(6)" ::: "memory");
        else if (kt == 10) asm volatile("s_waitcnt vmcnt(0)" ::: "memory");
        __builtin_amdgcn_s_barrier();

        s = (s + 1 == 3) ? 0 : s + 1;
    }

    // ---- epilogue ----
#pragma unroll
    for (int nf = 0; nf < 4; ++nf) {
        const int col = n0 + wn*64 + nf*16 + fr;
        const float bv = bias[col];
#pragma unroll
        for (int mf = 0; mf < 4; ++mf) {
            const int rowb = m0 + wm*64 + mf*16 + fq*4;
#pragma unroll
            for (int rr = 0; rr < 4; ++rr)
                oo[(size_t)(rowb + rr)*EMBD + col] = acc[mf][nf][rr] + bv;
        }
    }
}

// ---------------- FALLBACK GEMM (round-0, f32 reg-staged) -------------------
__global__ __launch_bounds__(256, 2)
void embed_gemm_kernel(const float* __restrict__ x1, const float* __restrict__ xx2,
                       const float* __restrict__ Wm, const float* __restrict__ bias,
                       float* __restrict__ out) {
    __shared__ __align__(16) unsigned char As[128*64*2];
    __shared__ __align__(16) unsigned char Bs[128*64*2];

    const float* __restrict__ xin = blockIdx.y ? xx2 : x1;
    float* __restrict__ oo = out + (size_t)blockIdx.y * (size_t)O2_OFS;

    const int bx = blockIdx.x;
    const int swz = (bx & 7) * (1728/8) + (bx >> 3);
    const int mt = swz / 6;
    const int nt = swz - mt * 6;
    const int m0 = mt * 128;
    const int n0 = nt * 128;

    const int tid = threadIdx.x;

    int boffA[8], boffB[8], lofs[8];
#pragma unroll
    for (int it = 0; it < 8; ++it) {
        const int ci = tid + 256*it;
        const int row = ci >> 4, col4 = ci & 15;
        const int m = m0 + row;
        const int bb = m / NPATCH;
        const int p  = m - bb*NPATCH;
        const int py = p / FS, px = p - py*FS;
        boffA[it] = ((bb*3)*IMGW + py*16 + (col4 >> 2)) * IMGW + px*16 + (col4 & 3)*4;
        boffB[it] = (n0 + row)*KDIM + col4*4;
        lofs[it]  = (ci*8) ^ ((row & 7) << 4);
    }

    f32x4 acc[4][4];
#pragma unroll
    for (int i = 0; i < 4; ++i)
#pragma unroll
        for (int j = 0; j < 4; ++j) acc[i][j] = (f32x4){0.f, 0.f, 0.f, 0.f};

    f32x4 stA[8], stB[8];
#pragma unroll
    for (int it = 0; it < 8; ++it) {
        stA[it] = *reinterpret_cast<const f32x4*>(xin + boffA[it]);
        stB[it] = *reinterpret_cast<const f32x4*>(Wm + boffB[it]);
    }

    const int l  = tid & 63;
    const int wid = tid >> 6;
    const int wr = wid >> 1, wc = wid & 1;
    const int fr = l & 15, fq = l >> 4;
    const int xorv = (fr & 7) << 4;

    for (int kt = 0; kt < 12; ++kt) {
        __syncthreads();
#pragma unroll
        for (int it = 0; it < 8; ++it) {
            *reinterpret_cast<u16x4*>(As + lofs[it]) = cvt4_bf16(stA[it]);
            *reinterpret_cast<u16x4*>(Bs + lofs[it]) = cvt4_bf16(stB[it]);
        }
        if (kt + 1 < 12) {
            const int dA = ((kt+1) >> 2) * (IMGW*IMGW) + ((kt+1) & 3) * (4*IMGW);
            const int dB = (kt+1) * 64;
#pragma unroll
            for (int it = 0; it < 8; ++it) {
                stA[it] = *reinterpret_cast<const f32x4*>(xin + boffA[it] + dA);
                stB[it] = *reinterpret_cast<const f32x4*>(Wm + boffB[it] + dB);
            }
        }
        __syncthreads();
#pragma unroll
        for (int ko = 0; ko < 2; ++ko) {
            const int colb = ko*64 + fq*16;
            bf16x8 af[4], bf4[4];
#pragma unroll
            for (int i = 0; i < 4; ++i) {
                const int ra = wr*64 + i*16 + fr;
                const int rb = wc*64 + i*16 + fr;
                af[i]  = *reinterpret_cast<const bf16x8*>(As + ra*128 + (colb ^ xorv));
                bf4[i] = *reinterpret_cast<const bf16x8*>(Bs + rb*128 + (colb ^ xorv));
            }
#pragma unroll
            for (int mi = 0; mi < 4; ++mi)
#pragma unroll
                for (int ni = 0; ni < 4; ++ni)
                    acc[mi][ni] = __builtin_amdgcn_mfma_f32_16x16x32_bf16(
                        af[mi], bf4[ni], acc[mi][ni], 0, 0, 0);
        }
    }

#pragma unroll
    for (int ni = 0; ni < 4; ++ni) {
        const int col = n0 + wc*64 + ni*16 + fr;
        const float bv = bias[col];
#pragma unroll
        for (int mi = 0; mi < 4; ++mi) {
            const int rowb = m0 + wr*64 + mi*16 + fq*4;
#pragma unroll
            for (int r = 0; r < 4; ++r)
                oo[(size_t)(rowb + r)*EMBD + col] = acc[mi][ni][r] + bv;
        }
    }
}

// ---------------- masked per-channel stats ----------------------------------
__global__ void stats_kernel(const float* __restrict__ o1, const float* __restrict__ o2,
                             float* __restrict__ ws) {
    const int b = blockIdx.y;
    const int c = blockIdx.x * 256 + threadIdx.x;

    float g1[4], g2[4];
#pragma unroll
    for (int i = 0; i < 4; ++i) { g1[i] = ws[WS_G1 + b*4 + i]; g2[i] = ws[WS_G2 + b*4 + i]; }

    for (int t = 0; t < 2; ++t) {
        const float* f = t ? o2 : o1;
        const float* g = t ? g2 : g1;
        int xlo = max(0, (int)g[0]);
        int xhi = min(FS, (int)g[2]);
        int ylo = max(0, (int)g[1]);
        int yhi = min(FS, (int)g[3]);
        float s = 0.f, ss = 0.f;
        for (int py = ylo; py < yhi; ++py)
            for (int px = xlo; px < xhi; ++px) {
                float v = f[(size_t)(b*NPATCH + py*FS + px)*EMBD + c];
                s += v; ss += v*v;
            }
        int nx = xhi - xlo; if (nx < 0) nx = 0;
        int ny = yhi - ylo; if (ny < 0) ny = 0;
        float n = (float)(nx*ny);
        float mean = s / fmaxf(n, 1.f);
        float var = (ss - 2.f*mean*s + n*mean*mean) / fmaxf(n - 1.f, 1.f);
        float sd = sqrtf(fmaxf(var, 0.f));
        ws[(t ? WS_MEAN2 : WS_MEAN1) + b*EMBD + c] = mean;
        ws[(t ? WS_STD2 : WS_STD1) + b*EMBD + c] = sd;
    }
}

// ---------------- blend (read-own / write-own, race-free) -------------------
__global__ void blend_kernel(float* __restrict__ o1, float* __restrict__ o2,
                             const float* __restrict__ ws) {
    const int b = blockIdx.y;
    const int p = blockIdx.x;
    const int py = p / FS, px = p - py*FS;
    const float pxf = (float)px, pyf = (float)py;

    const float sk1 = ws[WS_SK1 + b];
    const float sk2 = ws[WS_SK2 + b];
    const bool in1 = (pxf >= ws[WS_G1 + b*4+0]) && (pxf < ws[WS_G1 + b*4+2]) &&
                     (pyf >= ws[WS_G1 + b*4+1]) && (pyf < ws[WS_G1 + b*4+3]);
    const bool in2 = (pxf >= ws[WS_G2 + b*4+0]) && (pxf < ws[WS_G2 + b*4+2]) &&
                     (pyf >= ws[WS_G2 + b*4+1]) && (pyf < ws[WS_G2 + b*4+3]);
    const bool do1 = (sk1 == 0.f) && in2;
    const bool do2 = (sk2 == 0.f) && in1;
    if (!do1 && !do2) return;

    const int c = threadIdx.x * 4;
    const size_t base = (size_t)(b*NPATCH + p)*EMBD + c;
    const f32x4 f1 = *reinterpret_cast<const f32x4*>(o1 + base);
    const f32x4 f2 = *reinterpret_cast<const f32x4*>(o2 + base);
    const f32x4 m1 = *reinterpret_cast<const f32x4*>(ws + WS_MEAN1 + b*EMBD + c);
    const f32x4 s1 = *reinterpret_cast<const f32x4*>(ws + WS_STD1  + b*EMBD + c);
    const f32x4 m2 = *reinterpret_cast<const f32x4*>(ws + WS_MEAN2 + b*EMBD + c);
    const f32x4 s2 = *reinterpret_cast<const f32x4*>(ws + WS_STD2  + b*EMBD + c);

    if (do1) {
        f32x4 r;
#pragma unroll
        for (int j = 0; j < 4; ++j)
            r[j] = (f2[j] - m2[j]) / (s2[j] + EPSV) * (s1[j] + EPSV) + m1[j];
        *reinterpret_cast<f32x4*>(o1 + base) = r;
    }
    if (do2) {
        f32x4 r;
#pragma unroll
        for (int j = 0; j < 4; ++j)
            r[j] = (f1[j] - m1[j]) / (s1[j] + EPSV) * (s2[j] + EPSV) + m2[j];
        *reinterpret_cast<f32x4*>(o2 + base) = r;
    }
}

extern "C" void kernel_launch(void* const* d_in, const int* in_sizes, int n_in,
                              void* d_out, int out_size, void* d_ws, size_t ws_size,
                              hipStream_t stream) {
    const float* x    = (const float*)d_in[0];
    const float* x2   = (const float*)d_in[1];
    const float* gt1  = (const float*)d_in[2];
    const float* gt2  = (const float*)d_in[3];
    const float* Wm   = (const float*)d_in[4];
    const float* bias = (const float*)d_in[5];
    float* out = (float*)d_out;
    float* ws  = (float*)d_ws;

    float* o1 = out;
    float* o2 = out + O2_OFS;
    float* g1n = out + G1_OFS;
    float* g2n = out + G2_OFS;

    boxes_kernel<<<1, 64, 0, stream>>>(gt1, gt2, g1n, g2n, ws);

    if (ws_size >= WS_NEED) {
        unsigned short* Wb = (unsigned short*)((char*)d_ws + WSB_W);
        unsigned short* im = (unsigned short*)((char*)d_ws + WSB_IM);
        cvt_w_kernel<<<288, 256, 0, stream>>>(Wm, Wb);
        im2col_kernel<<<13824, 256, 0, stream>>>(x, im);
        gemm8_kernel<<<864, 512, 0, stream>>>(im, Wb, bias, o1);
        im2col_kernel<<<13824, 256, 0, stream>>>(x2, im);
        gemm8_kernel<<<864, 512, 0, stream>>>(im, Wb, bias, o2);
    } else {
        embed_gemm_kernel<<<dim3(1728, 2), 256, 0, stream>>>(x, x2, Wm, bias, out);
    }

    stats_kernel<<<dim3(3, NB), 256, 0, stream>>>(o1, o2, ws);
    blend_kernel<<<dim3(NPATCH, NB), 192, 0, stream>>>(o1, o2, ws);
}

// Round 4
// 250.789 us; speedup vs baseline: 1.0193x; 1.0193x over previous
//
#include <hip/hip_runtime.h>
#include <hip/hip_bf16.h>

#define FS 24
#define NPATCH 576
#define EMBD 768
#define KDIM 768
#define NB 64
#define IMGW 384
#define MTOT (NB*NPATCH)       // 36864
#define EPSV 1e-4f

#define O2_OFS (MTOT*EMBD)     // 28311552
#define G1_OFS (2*O2_OFS)      // 56623104
#define G2_OFS (G1_OFS + NB*4)

// workspace float-region layout (float indices at byte offset 0)
#define WS_G1 0
#define WS_G2 256
#define WS_SK1 512
#define WS_SK2 576
#define WS_MEAN1 1024
#define WS_STD1 (WS_MEAN1 + NB*EMBD)
#define WS_MEAN2 (WS_STD1 + NB*EMBD)
#define WS_STD2 (WS_MEAN2 + NB*EMBD)

// bf16 W lives at byte offset 1 MiB in ws (float region ends ~790 KB)
#define WSB_W  1048576ULL
#define WS_NEED (WSB_W + 1179648ULL)   // 2,228,224 B

typedef __attribute__((ext_vector_type(8))) short bf16x8;
typedef __attribute__((ext_vector_type(4))) unsigned short u16x4;
typedef __attribute__((ext_vector_type(8))) unsigned short u16x8;
typedef __attribute__((ext_vector_type(4))) float f32x4;

__device__ __forceinline__ u16x4 cvt4_bf16(f32x4 v) {
    u16x4 r;
#pragma unroll
    for (int j = 0; j < 4; ++j) r[j] = __builtin_bit_cast(unsigned short, (__bf16)v[j]);
    return r;
}

// ---------------- boxes: per-batch scalar pipeline (exact f32 port) ----------
__device__ inline float occ_of(const float b1[4], const float b2[4]) {
    float ixmin = fmaxf(b1[0], b2[0]);
    float iymin = fmaxf(b1[1], b2[1]);
    float ixmax = fminf(b1[2], b2[2]);
    float iymax = fminf(b1[3], b2[3]);
    float iv = fmaxf(iymax - iymin, 0.f) * fmaxf(ixmax - ixmin, 0.f);
    float v1 = (b1[2] - b1[0]) * (b1[3] - b1[1]);
    return (iv + 1e-8f) / (v1 + 1e-8f);
}

__device__ inline void upd_box(const float* b1, const float* b2, float* o) {
    float x0 = b1[0], y0 = b1[1], x2 = b1[2], y2 = b1[3];
    float q0 = b2[0], q1 = b2[1], q2 = b2[2], q3 = b2[3];
    bool condA = (x0 >= q0) && (x2 <= q2);
    bool subA1 = (q1 <= y0) && (q3 > y0);
    bool a1 = condA && subA1;
    bool a2 = condA && !subA1 && (q3 >= y2) && (q1 < y2);
    bool condB = !condA && (y0 >= q1) && (y2 <= q3);
    bool subB1 = (q0 <= x0) && (q2 > x0);
    bool bb1 = condB && subB1;
    bool bb2 = condB && !subB1 && (q2 >= x2) && (q0 < x2);
    o[1] = a1 ? q3 : y0;
    o[3] = a2 ? q1 : y2;
    o[0] = bb1 ? q2 : x0;
    o[2] = bb2 ? q0 : x2;
}

__global__ void boxes_kernel(const float* __restrict__ gt1, const float* __restrict__ gt2,
                             float* __restrict__ gout1, float* __restrict__ gout2,
                             float* __restrict__ ws) {
    const int b = threadIdx.x;
    if (b >= NB) return;
    float g1[4], g2[4];
    {
        float p0 = gt1[b*4+0]*(float)IMGW, p1 = gt1[b*4+1]*(float)IMGW;
        float p2 = gt1[b*4+2]*(float)IMGW, p3 = gt1[b*4+3]*(float)IMGW;
        g1[0] = rintf(p0 / 16.f);
        g1[1] = rintf(p1 / 16.f);
        g1[2] = rintf((p0 + p2 - 1.f) / 16.f);
        g1[3] = rintf((p1 + p3 - 1.f) / 16.f);
    }
    {
        float p0 = gt2[b*4+0]*(float)IMGW, p1 = gt2[b*4+1]*(float)IMGW;
        float p2 = gt2[b*4+2]*(float)IMGW, p3 = gt2[b*4+3]*(float)IMGW;
        g2[0] = rintf(p0 / 16.f);
        g2[1] = rintf(p1 / 16.f);
        g2[2] = rintf((p0 + p2 - 1.f) / 16.f);
        g2[3] = rintf((p1 + p3 - 1.f) / 16.f);
    }
    float occ1 = occ_of(g1, g2), occ2 = occ_of(g2, g1);
    const float fsf = (float)FS;
    bool skip1 = (occ1 > 0.5f) || (g2[3] <= g2[1]) || (g2[2] <= g2[0]) ||
                 (g2[0] < 0.f) || (g2[1] < 0.f) || (g2[0] >= fsf) || (g2[1] >= fsf);
    bool skip2 = (occ2 > 0.5f) || (g1[3] <= g1[1]) || (g1[2] <= g1[0]) ||
                 (g1[0] < 0.f) || (g1[1] < 0.f) || (g1[0] >= fsf) || (g1[1] >= fsf);

    float n1[4], n2[4];
    upd_box(g1, g2, n1);
    upd_box(g2, g1, n2);
    if (skip1) { n1[0]=g1[0]; n1[1]=g1[1]; n1[2]=g1[2]; n1[3]=g1[3]; }
    if (skip2) { n2[0]=g2[0]; n2[1]=g2[1]; n2[2]=g2[2]; n2[3]=g2[3]; }

    gout1[b*4+0] = n1[0]; gout1[b*4+1] = n1[1];
    gout1[b*4+2] = n1[2] - n1[0]; gout1[b*4+3] = n1[3] - n1[1];
    gout2[b*4+0] = n2[0]; gout2[b*4+1] = n2[1];
    gout2[b*4+2] = n2[2] - n2[0]; gout2[b*4+3] = n2[3] - n2[1];

#pragma unroll
    for (int i = 0; i < 4; ++i) { ws[WS_G1 + b*4 + i] = g1[i]; ws[WS_G2 + b*4 + i] = g2[i]; }
    ws[WS_SK1 + b] = skip1 ? 1.f : 0.f;
    ws[WS_SK2 + b] = skip2 ? 1.f : 0.f;
}

// ---- pre-convert W f32 -> bf16, LINEAR [n][k] (swizzle applied at ds_write) -
__global__ void cvt_w_kernel(const float* __restrict__ Wm, unsigned short* __restrict__ Wb) {
    const int idx = blockIdx.x * 256 + threadIdx.x;   // 73728 chunks of 8
    const f32x4 a = *reinterpret_cast<const f32x4*>(Wm + idx*8);
    const f32x4 b = *reinterpret_cast<const f32x4*>(Wm + idx*8 + 4);
    u16x8 r;
    u16x4 lo = cvt4_bf16(a), hi = cvt4_bf16(b);
#pragma unroll
    for (int j = 0; j < 4; ++j) { r[j] = lo[j]; r[j+4] = hi[j]; }
    *reinterpret_cast<u16x8*>(Wb + idx*8) = r;
}

// ---- fused im2col + bf16 GEMM --------------------------------------------
// 128x128 tile, BK=64, 4 waves (2x2), dbuf LDS (64 KiB -> 2 blocks/CU),
// reg-staged A (f32 x -> cvt) + B (bf16 W), 2-deep pipeline,
// raw s_barrier + lgkmcnt(0) only: global loads stay in flight across barriers.
#define GEMM_STEP(KT, WA, WB, LA, LB, CBUF)                                        \
  {                                                                                \
    const int kt_ = (KT);                                                          \
    if (kt_ + 1 < 12) {                                                            \
      unsigned char* Aw = ldsA + ((CBUF)^1)*16384;                                 \
      unsigned char* Bw = ldsB + ((CBUF)^1)*16384;                                 \
      _Pragma("unroll")                                                            \
      for (int j = 0; j < 4; ++j) {                                                \
        u16x4 lo = cvt4_bf16(WA[j][0]), hi = cvt4_bf16(WA[j][1]);                  \
        u16x8 v;                                                                   \
        _Pragma("unroll")                                                          \
        for (int q = 0; q < 4; ++q) { v[q] = lo[q]; v[q+4] = hi[q]; }              \
        *reinterpret_cast<u16x8*>(Aw + lofsA[j]) = v;                              \
      }                                                                            \
      _Pragma("unroll")                                                            \
      for (int j = 0; j < 4; ++j)                                                  \
        *reinterpret_cast<u16x8*>(Bw + lofsB[j]) = WB[j];                          \
    }                                                                              \
    if (kt_ + 2 < 12) {                                                            \
      const int dA = ((kt_+2) >> 2)*(IMGW*IMGW) + ((kt_+2) & 3)*(4*IMGW);          \
      _Pragma("unroll")                                                            \
      for (int j = 0; j < 4; ++j) {                                                \
        LA[j][0] = *reinterpret_cast<const f32x4*>(xin + boffA[j] + dA);           \
        LA[j][1] = *reinterpret_cast<const f32x4*>(xin + boffA[j] + dA + 4);       \
      }                                                                            \
      _Pragma("unroll")                                                            \
      for (int j = 0; j < 4; ++j)                                                  \
        LB[j] = *reinterpret_cast<const u16x8*>(Wb + boffB[j] + (kt_+2)*64);       \
    }                                                                              \
    {                                                                              \
      const unsigned char* Ar = ldsA + (CBUF)*16384;                               \
      const unsigned char* Br = ldsB + (CBUF)*16384;                               \
      _Pragma("unroll")                                                            \
      for (int ko = 0; ko < 2; ++ko) {                                             \
        const int colb = ko*64 + fq*16;                                            \
        bf16x8 af[4], bfv[4];                                                      \
        _Pragma("unroll")                                                          \
        for (int i = 0; i < 4; ++i) {                                              \
          af[i]  = *reinterpret_cast<const bf16x8*>(Ar + (wr*64 + i*16 + fr)*128 + (colb ^ xorv)); \
          bfv[i] = *reinterpret_cast<const bf16x8*>(Br + (wc*64 + i*16 + fr)*128 + (colb ^ xorv)); \
        }                                                                          \
        __builtin_amdgcn_s_setprio(1);                                             \
        _Pragma("unroll")                                                          \
        for (int mi = 0; mi < 4; ++mi)                                             \
          _Pragma("unroll")                                                        \
          for (int ni = 0; ni < 4; ++ni)                                           \
            acc[mi][ni] = __builtin_amdgcn_mfma_f32_16x16x32_bf16(                 \
                af[mi], bfv[ni], acc[mi][ni], 0, 0, 0);                            \
        __builtin_amdgcn_s_setprio(0);                                             \
      }                                                                            \
    }                                                                              \
    asm volatile("s_waitcnt lgkmcnt(0)\n\ts_barrier" ::: "memory");                \
  }

__global__ __launch_bounds__(256, 2)
void fused_gemm_kernel(const float* __restrict__ x1, const float* __restrict__ xx2,
                       const unsigned short* __restrict__ Wb,
                       const float* __restrict__ bias,
                       float* __restrict__ out) {
    __shared__ __align__(16) unsigned char ldsA[2*16384];
    __shared__ __align__(16) unsigned char ldsB[2*16384];

    const float* __restrict__ xin = blockIdx.y ? xx2 : x1;
    float* __restrict__ oo = out + (size_t)blockIdx.y * (size_t)O2_OFS;

    // XCD swizzle; consecutive swz share the A-panel across the 6 n-tiles
    const int bx = blockIdx.x;
    const int swz = (bx & 7) * 216 + (bx >> 3);
    const int mt = swz / 6;
    const int nt = swz - mt * 6;
    const int m0 = mt * 128;
    const int n0 = nt * 128;

    const int tid = threadIdx.x;

    // A: 1024 chunks of 8 floats; 4 per thread. B: 1024 chunks of 16 B; 4 per thread.
    int boffA[4], lofsA[4], boffB[4], lofsB[4];
#pragma unroll
    for (int j = 0; j < 4; ++j) {
        const int ci = tid + 256*j;          // 0..1023
        const int row = ci >> 3, c8 = ci & 7;
        const int m = m0 + row;
        const int bb = m / NPATCH;
        const int p  = m - bb*NPATCH;
        const int py = p / FS, px = p - py*FS;
        // k = kt*64 + c8*8 -> ch = kt>>2, i = (kt&3)*4 + (c8>>1), jj = (c8&1)*8
        boffA[j] = ((bb*3)*IMGW + py*16 + (c8 >> 1)) * IMGW + px*16 + (c8 & 1)*8;
        lofsA[j] = (ci*16) ^ ((row & 7) << 4);
        boffB[j] = (n0 + row)*KDIM + c8*8;
        lofsB[j] = lofsA[j];
    }

    f32x4 acc[4][4];
#pragma unroll
    for (int i = 0; i < 4; ++i)
#pragma unroll
        for (int j = 0; j < 4; ++j) acc[i][j] = (f32x4){0.f, 0.f, 0.f, 0.f};

    const int l  = tid & 63;
    const int wid = tid >> 6;
    const int wr = wid >> 1, wc = wid & 1;
    const int fr = l & 15, fq = l >> 4;
    const int xorv = (fr & 7) << 4;

    // prologue: issue tile0 + tile1 loads, write tile0 to buf0
    f32x4 sA0[4][2], sA1[4][2];
    u16x8 sB0[4], sB1[4];
#pragma unroll
    for (int j = 0; j < 4; ++j) {
        sA0[j][0] = *reinterpret_cast<const f32x4*>(xin + boffA[j]);
        sA0[j][1] = *reinterpret_cast<const f32x4*>(xin + boffA[j] + 4);
        sB0[j]    = *reinterpret_cast<const u16x8*>(Wb + boffB[j]);
    }
#pragma unroll
    for (int j = 0; j < 4; ++j) {
        sA1[j][0] = *reinterpret_cast<const f32x4*>(xin + boffA[j] + 4*IMGW);
        sA1[j][1] = *reinterpret_cast<const f32x4*>(xin + boffA[j] + 4*IMGW + 4);
        sB1[j]    = *reinterpret_cast<const u16x8*>(Wb + boffB[j] + 64);
    }
#pragma unroll
    for (int j = 0; j < 4; ++j) {
        u16x4 lo = cvt4_bf16(sA0[j][0]), hi = cvt4_bf16(sA0[j][1]);
        u16x8 v;
#pragma unroll
        for (int q = 0; q < 4; ++q) { v[q] = lo[q]; v[q+4] = hi[q]; }
        *reinterpret_cast<u16x8*>(ldsA + lofsA[j]) = v;
        *reinterpret_cast<u16x8*>(ldsB + lofsB[j]) = sB0[j];
    }
    asm volatile("s_waitcnt lgkmcnt(0)\n\ts_barrier" ::: "memory");

    for (int kt = 0; kt < 12; kt += 2) {
        GEMM_STEP(kt,   sA1, sB1, sA0, sB0, 0);   // compute buf0; write t(kt+1); load t(kt+2)
        GEMM_STEP(kt+1, sA0, sB0, sA1, sB1, 1);   // compute buf1; write t(kt+2); load t(kt+3)
    }

    // epilogue
#pragma unroll
    for (int ni = 0; ni < 4; ++ni) {
        const int col = n0 + wc*64 + ni*16 + fr;
        const float bv = bias[col];
#pragma unroll
        for (int mi = 0; mi < 4; ++mi) {
            const int rowb = m0 + wr*64 + mi*16 + fq*4;
#pragma unroll
            for (int r = 0; r < 4; ++r)
                oo[(size_t)(rowb + r)*EMBD + col] = acc[mi][ni][r] + bv;
        }
    }
}

// ---------------- FALLBACK GEMM (round-0, f32 reg-staged, 2-barrier) --------
__global__ __launch_bounds__(256, 2)
void embed_gemm_kernel(const float* __restrict__ x1, const float* __restrict__ xx2,
                       const float* __restrict__ Wm, const float* __restrict__ bias,
                       float* __restrict__ out) {
    __shared__ __align__(16) unsigned char As[128*64*2];
    __shared__ __align__(16) unsigned char Bs[128*64*2];

    const float* __restrict__ xin = blockIdx.y ? xx2 : x1;
    float* __restrict__ oo = out + (size_t)blockIdx.y * (size_t)O2_OFS;

    const int bx = blockIdx.x;
    const int swz = (bx & 7) * (1728/8) + (bx >> 3);
    const int mt = swz / 6;
    const int nt = swz - mt * 6;
    const int m0 = mt * 128;
    const int n0 = nt * 128;

    const int tid = threadIdx.x;

    int boffA[8], boffB[8], lofs[8];
#pragma unroll
    for (int it = 0; it < 8; ++it) {
        const int ci = tid + 256*it;
        const int row = ci >> 4, col4 = ci & 15;
        const int m = m0 + row;
        const int bb = m / NPATCH;
        const int p  = m - bb*NPATCH;
        const int py = p / FS, px = p - py*FS;
        boffA[it] = ((bb*3)*IMGW + py*16 + (col4 >> 2)) * IMGW + px*16 + (col4 & 3)*4;
        boffB[it] = (n0 + row)*KDIM + col4*4;
        lofs[it]  = (ci*8) ^ ((row & 7) << 4);
    }

    f32x4 acc[4][4];
#pragma unroll
    for (int i = 0; i < 4; ++i)
#pragma unroll
        for (int j = 0; j < 4; ++j) acc[i][j] = (f32x4){0.f, 0.f, 0.f, 0.f};

    f32x4 stA[8], stB[8];
#pragma unroll
    for (int it = 0; it < 8; ++it) {
        stA[it] = *reinterpret_cast<const f32x4*>(xin + boffA[it]);
        stB[it] = *reinterpret_cast<const f32x4*>(Wm + boffB[it]);
    }

    const int l  = tid & 63;
    const int wid = tid >> 6;
    const int wr = wid >> 1, wc = wid & 1;
    const int fr = l & 15, fq = l >> 4;
    const int xorv = (fr & 7) << 4;

    for (int kt = 0; kt < 12; ++kt) {
        __syncthreads();
#pragma unroll
        for (int it = 0; it < 8; ++it) {
            *reinterpret_cast<u16x4*>(As + lofs[it]) = cvt4_bf16(stA[it]);
            *reinterpret_cast<u16x4*>(Bs + lofs[it]) = cvt4_bf16(stB[it]);
        }
        if (kt + 1 < 12) {
            const int dA = ((kt+1) >> 2) * (IMGW*IMGW) + ((kt+1) & 3) * (4*IMGW);
            const int dB = (kt+1) * 64;
#pragma unroll
            for (int it = 0; it < 8; ++it) {
                stA[it] = *reinterpret_cast<const f32x4*>(xin + boffA[it] + dA);
                stB[it] = *reinterpret_cast<const f32x4*>(Wm + boffB[it] + dB);
            }
        }
        __syncthreads();
#pragma unroll
        for (int ko = 0; ko < 2; ++ko) {
            const int colb = ko*64 + fq*16;
            bf16x8 af[4], bf4[4];
#pragma unroll
            for (int i = 0; i < 4; ++i) {
                af[i]  = *reinterpret_cast<const bf16x8*>(As + (wr*64 + i*16 + fr)*128 + (colb ^ xorv));
                bf4[i] = *reinterpret_cast<const bf16x8*>(Bs + (wc*64 + i*16 + fr)*128 + (colb ^ xorv));
            }
#pragma unroll
            for (int mi = 0; mi < 4; ++mi)
#pragma unroll
                for (int ni = 0; ni < 4; ++ni)
                    acc[mi][ni] = __builtin_amdgcn_mfma_f32_16x16x32_bf16(
                        af[mi], bf4[ni], acc[mi][ni], 0, 0, 0);
        }
    }

#pragma unroll
    for (int ni = 0; ni < 4; ++ni) {
        const int col = n0 + wc*64 + ni*16 + fr;
        const float bv = bias[col];
#pragma unroll
        for (int mi = 0; mi < 4; ++mi) {
            const int rowb = m0 + wr*64 + mi*16 + fq*4;
#pragma unroll
            for (int r = 0; r < 4; ++r)
                oo[(size_t)(rowb + r)*EMBD + col] = acc[mi][ni][r] + bv;
        }
    }
}

// ---------------- masked per-channel stats ----------------------------------
__global__ void stats_kernel(const float* __restrict__ o1, const float* __restrict__ o2,
                             float* __restrict__ ws) {
    const int b = blockIdx.y;
    const int c = blockIdx.x * 256 + threadIdx.x;

    float g1[4], g2[4];
#pragma unroll
    for (int i = 0; i < 4; ++i) { g1[i] = ws[WS_G1 + b*4 + i]; g2[i] = ws[WS_G2 + b*4 + i]; }

    for (int t = 0; t < 2; ++t) {
        const float* f = t ? o2 : o1;
        const float* g = t ? g2 : g1;
        int xlo = max(0, (int)g[0]);
        int xhi = min(FS, (int)g[2]);
        int ylo = max(0, (int)g[1]);
        int yhi = min(FS, (int)g[3]);
        float s = 0.f, ss = 0.f;
        for (int py = ylo; py < yhi; ++py)
            for (int px = xlo; px < xhi; ++px) {
                float v = f[(size_t)(b*NPATCH + py*FS + px)*EMBD + c];
                s += v; ss += v*v;
            }
        int nx = xhi - xlo; if (nx < 0) nx = 0;
        int ny = yhi - ylo; if (ny < 0) ny = 0;
        float n = (float)(nx*ny);
        float mean = s / fmaxf(n, 1.f);
        float var = (ss - 2.f*mean*s + n*mean*mean) / fmaxf(n - 1.f, 1.f);
        float sd = sqrtf(fmaxf(var, 0.f));
        ws[(t ? WS_MEAN2 : WS_MEAN1) + b*EMBD + c] = mean;
        ws[(t ? WS_STD2 : WS_STD1) + b*EMBD + c] = sd;
    }
}

// ---------------- blend (read-own / write-own, race-free) -------------------
__global__ void blend_kernel(float* __restrict__ o1, float* __restrict__ o2,
                             const float* __restrict__ ws) {
    const int b = blockIdx.y;
    const int p = blockIdx.x;
    const int py = p / FS, px = p - py*FS;
    const float pxf = (float)px, pyf = (float)py;

    const float sk1 = ws[WS_SK1 + b];
    const float sk2 = ws[WS_SK2 + b];
    const bool in1 = (pxf >= ws[WS_G1 + b*4+0]) && (pxf < ws[WS_G1 + b*4+2]) &&
                     (pyf >= ws[WS_G1 + b*4+1]) && (pyf < ws[WS_G1 + b*4+3]);
    const bool in2 = (pxf >= ws[WS_G2 + b*4+0]) && (pxf < ws[WS_G2 + b*4+2]) &&
                     (pyf >= ws[WS_G2 + b*4+1]) && (pyf < ws[WS_G2 + b*4+3]);
    const bool do1 = (sk1 == 0.f) && in2;
    const bool do2 = (sk2 == 0.f) && in1;
    if (!do1 && !do2) return;

    const int c = threadIdx.x * 4;
    const size_t base = (size_t)(b*NPATCH + p)*EMBD + c;
    const f32x4 f1 = *reinterpret_cast<const f32x4*>(o1 + base);
    const f32x4 f2 = *reinterpret_cast<const f32x4*>(o2 + base);
    const f32x4 m1 = *reinterpret_cast<const f32x4*>(ws + WS_MEAN1 + b*EMBD + c);
    const f32x4 s1 = *reinterpret_cast<const f32x4*>(ws + WS_STD1  + b*EMBD + c);
    const f32x4 m2 = *reinterpret_cast<const f32x4*>(ws + WS_MEAN2 + b*EMBD + c);
    const f32x4 s2 = *reinterpret_cast<const f32x4*>(ws + WS_STD2  + b*EMBD + c);

    if (do1) {
        f32x4 r;
#pragma unroll
        for (int j = 0; j < 4; ++j)
            r[j] = (f2[j] - m2[j]) / (s2[j] + EPSV) * (s1[j] + EPSV) + m1[j];
        *reinterpret_cast<f32x4*>(o1 + base) = r;
    }
    if (do2) {
        f32x4 r;
#pragma unroll
        for (int j = 0; j < 4; ++j)
            r[j] = (f1[j] - m1[j]) / (s1[j] + EPSV) * (s2[j] + EPSV) + m2[j];
        *reinterpret_cast<f32x4*>(o2 + base) = r;
    }
}

extern "C" void kernel_launch(void* const* d_in, const int* in_sizes, int n_in,
                              void* d_out, int out_size, void* d_ws, size_t ws_size,
                              hipStream_t stream) {
    const float* x    = (const float*)d_in[0];
    const float* x2   = (const float*)d_in[1];
    const float* gt1  = (const float*)d_in[2];
    const float* gt2  = (const float*)d_in[3];
    const float* Wm   = (const float*)d_in[4];
    const float* bias = (const float*)d_in[5];
    float* out = (float*)d_out;
    float* ws  = (float*)d_ws;

    float* o1 = out;
    float* o2 = out + O2_OFS;
    float* g1n = out + G1_OFS;
    float* g2n = out + G2_OFS;

    boxes_kernel<<<1, 64, 0, stream>>>(gt1, gt2, g1n, g2n, ws);

    if (ws_size >= WS_NEED) {
        unsigned short* Wb = (unsigned short*)((char*)d_ws + WSB_W);
        cvt_w_kernel<<<288, 256, 0, stream>>>(Wm, Wb);
        fused_gemm_kernel<<<dim3(1728, 2), 256, 0, stream>>>(x, x2, Wb, bias, out);
    } else {
        embed_gemm_kernel<<<dim3(1728, 2), 256, 0, stream>>>(x, x2, Wm, bias, out);
    }

    stats_kernel<<<dim3(3, NB), 256, 0, stream>>>(o1, o2, ws);
    blend_kernel<<<dim3(NPATCH, NB), 192, 0, stream>>>(o1, o2, ws);
}